// Round 8
// baseline (454.611 us; speedup 1.0000x reference)
//
#include <hip/hip_runtime.h>
#include <hip/hip_bf16.h>
#include <stdint.h>

// Problem constants
#define BB 4
#define SS 2048
#define DD 1024
#define HH 16
#define DHH 128   // per-head dim after concat (2*64)

typedef __bf16 bf16x8 __attribute__((ext_vector_type(8)));
typedef __bf16 bf16x4 __attribute__((ext_vector_type(4)));
typedef float  f32x4  __attribute__((ext_vector_type(4)));

// (1/sqrt(64)) * log2(e), folded into Q at GEMM epilogue time
#define SL2E 0.180336880111186f

#if __has_builtin(__builtin_amdgcn_exp2f)
#define EXP2(x) __builtin_amdgcn_exp2f(x)
#else
#define EXP2(x) exp2f(x)
#endif

// async global->LDS, 16B per lane; LDS dest is wave-uniform base + lane*16,
// global src is per-lane (gather allowed)
#define GLOAD_LDS16(gp, lp) \
  __builtin_amdgcn_global_load_lds((const __attribute__((address_space(1))) unsigned int*)(gp), \
                                   (__attribute__((address_space(3))) unsigned int*)(lp), 16, 0, 0)

// compiler memory fence around raw s_barrier so LDS ops can't be moved across
#define SBAR() do { asm volatile("" ::: "memory"); \
                    __builtin_amdgcn_s_barrier();  \
                    asm volatile("" ::: "memory"); } while (0)

#define MFMA_BF16(a, b, c) __builtin_amdgcn_mfma_f32_16x16x32_bf16((a), (b), (c), 0, 0, 0)

// ---------------------------------------------------------------------------
// Fused cast of x and c -> bf16 (dest xb and cb are contiguous)
__global__ void cast2_kernel(const float* __restrict__ x, const float* __restrict__ c,
                             __bf16* __restrict__ out, int n) {
    int i = (blockIdx.x * blockDim.x + threadIdx.x) * 4;
    const float* src = (i < n) ? (x + i) : (c + (i - n));
    f32x4 v = *(const f32x4*)src;
    bf16x4 o;
    o[0] = (__bf16)v[0]; o[1] = (__bf16)v[1]; o[2] = (__bf16)v[2]; o[3] = (__bf16)v[3];
    *(bf16x4*)(out + i) = o;
}

// ---------------------------------------------------------------------------
// Transpose + cast: W[K][N] fp32 -> Wt[N][K] bf16 (used for W_proj)
__global__ void transpose_cast_kernel(const float* __restrict__ in, __bf16* __restrict__ out,
                                      int K, int N) {
    __shared__ float tile[32][33];
    int n0 = blockIdx.x * 32, k0 = blockIdx.y * 32;
    int tx = threadIdx.x, ty = threadIdx.y;   // 32 x 8
    #pragma unroll
    for (int i = 0; i < 32; i += 8)
        tile[ty + i][tx] = in[(size_t)(k0 + ty + i) * N + n0 + tx];
    __syncthreads();
    #pragma unroll
    for (int i = 0; i < 32; i += 8)
        out[(size_t)(n0 + ty + i) * K + k0 + tx] = (__bf16)tile[tx][ty + i];
}

// Fused transpose+cast of the six 1024x1024 QKV weights into contiguous dst
// Order: Wq_x, Wk_x, Wv_x, Wq_c, Wk_c, Wv_c  (Q,K adjacent per input for fusion)
__global__ void transpose6_kernel(const float* s0, const float* s1, const float* s2,
                                  const float* s3, const float* s4, const float* s5,
                                  __bf16* __restrict__ dst) {
    const float* srcs[6] = {s0, s1, s2, s3, s4, s5};
    const float* __restrict__ in = srcs[blockIdx.z];
    __bf16* __restrict__ out = dst + (size_t)blockIdx.z * 1024 * 1024;
    __shared__ float tile[32][33];
    int n0 = blockIdx.x * 32, k0 = blockIdx.y * 32;
    int tx = threadIdx.x, ty = threadIdx.y;   // 32 x 8
    #pragma unroll
    for (int i = 0; i < 32; i += 8)
        tile[ty + i][tx] = in[(size_t)(k0 + ty + i) * 1024 + n0 + tx];
    __syncthreads();
    #pragma unroll
    for (int i = 0; i < 32; i += 8)
        out[(size_t)(n0 + ty + i) * 1024 + k0 + tx] = (__bf16)tile[tx][ty + i];
}

// ---------------------------------------------------------------------------
// 256x256 pipelined GEMM: C = A @ Bt^T (bf16, both contiguous in K).
// 512 threads = 8 waves (2x4), per-wave 128x64 output (acc 8x4).
// BK=32; LDS ring of 4 x 32KB; staging 3 tiles ahead (global_load_lds).
// Fragments read ONE PHASE AHEAD of their MFMA (LDS service overlaps the
// previous MFMA cluster); next-tile reads AFTER the barrier that follows the
// counted vmcnt. vmcnt never drains to 0 until the 2-tile epilogue.
template <int EPI>
__global__ __launch_bounds__(512, 2)
void gemm256_kernel(const __bf16* __restrict__ A0, const __bf16* __restrict__ A1,
                    const __bf16* __restrict__ B0, const __bf16* __restrict__ B1,
                    int K, void* __restrict__ outp, const float* __restrict__ bias) {
    const int z = blockIdx.z;
    const __bf16* __restrict__ A  = z ? A1 : A0;
    const __bf16* __restrict__ Bt = z ? B1 : B0;
    const int qkv_off = z * 64;

    __shared__ __align__(16) char smem[131072];   // 4 x (A 16KB @0 + B 16KB @16384)

    const int tid = threadIdx.x;
    const int wave = tid >> 6, lane = tid & 63;
    const int l15 = lane & 15, quad = lane >> 4;
    const int wr = wave >> 2, wc = wave & 3;      // wave -> (row half, col quarter)

    // XCD-aware block remap (bijective: nwg per z is a multiple of 8)
    const int gx = gridDim.x;
    const int nwg = gx * gridDim.y;
    const int hwl = blockIdx.y * gx + blockIdx.x;
    const int lg  = (hwl & 7) * (nwg >> 3) + (hwl >> 3);
    const int m0 = (lg % gx) * 256, n0 = (lg / gx) * 256;

    // staging: thread tid covers (r = j*128 + tid/4, chunk = tid&3), j=0,1
    // global source chunk pre-swizzled: c_src = (tid&3) ^ ((r>>2)&3)
    const int rA = tid >> 2;
    const int cs = (tid & 3) ^ ((tid >> 4) & 3);
    const __bf16* aS0 = A  + (size_t)(m0 + rA) * K + cs * 8;
    const __bf16* aS1 = aS0 + (size_t)128 * K;
    const __bf16* bS0 = Bt + (size_t)(n0 + rA) * K + cs * 8;
    const __bf16* bS1 = bS0 + (size_t)128 * K;
    const int ldsA = wave * 1024;            // + j*8192 + buf*32768 (lane*16 by HW)
    const int ldsB = 16384 + wave * 1024;

    // ds_read bases: row r, byte = r*64 + ((quad ^ ((r>>2)&3))&3)*16
    const int swz = ((quad ^ (l15 >> 2)) & 3) * 16;
    const int ra = (wr * 128 + l15) * 64 + swz;            // + mi*1024 + buf
    const int rb = 16384 + (wc * 64 + l15) * 64 + swz;     // + ni*1024 + buf

    f32x4 acc[8][4] = {};
    bf16x8 afc[2][4], bfc[2][4], afB[4];
    const int NT = K >> 5;

    #define STAGE_A(tt) do { const int bo_ = ((tt) & 3) * 32768; \
        GLOAD_LDS16(aS0 + (size_t)(tt) * 32, smem + bo_ + ldsA); \
        GLOAD_LDS16(aS1 + (size_t)(tt) * 32, smem + bo_ + ldsA + 8192); } while (0)
    #define STAGE_B(tt) do { const int bo_ = ((tt) & 3) * 32768; \
        GLOAD_LDS16(bS0 + (size_t)(tt) * 32, smem + bo_ + ldsB); \
        GLOAD_LDS16(bS1 + (size_t)(tt) * 32, smem + bo_ + ldsB + 8192); } while (0)

    // prologue: stage tiles 0..2; wait tile 0 (8 younger in flight); read set0
    STAGE_A(0); STAGE_B(0);
    STAGE_A(1); STAGE_B(1);
    STAGE_A(2); STAGE_B(2);
    asm volatile("s_waitcnt vmcnt(8)" ::: "memory");
    SBAR();
    #pragma unroll
    for (int i = 0; i < 4; ++i) afc[0][i] = *(const bf16x8*)(smem + ra + i * 1024);
    #pragma unroll
    for (int i = 0; i < 4; ++i) bfc[0][i] = *(const bf16x8*)(smem + rb + i * 1024);

    for (int tp = 0; tp < NT / 2; ++tp) {
        #pragma unroll
        for (int u = 0; u < 2; ++u) {
            const int t = 2 * tp + u;
            const int co = (t & 3) * 32768;
            const int cn = ((t + 1) & 3) * 32768;
            // ---------------- phase 1 ----------------
            #pragma unroll
            for (int i = 0; i < 4; ++i)
                afB[i] = *(const bf16x8*)(smem + co + ra + (4 + i) * 1024);
            if (t + 3 < NT) STAGE_A(t + 3);
            SBAR();
            __builtin_amdgcn_s_setprio(1);
            #pragma unroll
            for (int mi = 0; mi < 4; ++mi)
                #pragma unroll
                for (int ni = 0; ni < 4; ++ni)
                    acc[mi][ni] = MFMA_BF16(afc[u][mi], bfc[u][ni], acc[mi][ni]);
            __builtin_amdgcn_s_setprio(0);
            // ---------------- phase 2 ----------------
            if (t + 3 < NT) STAGE_B(t + 3);
            if (t < NT - 3)       asm volatile("s_waitcnt vmcnt(8)" ::: "memory");
            else if (t == NT - 3) asm volatile("s_waitcnt vmcnt(4)" ::: "memory");
            else if (t == NT - 2) asm volatile("s_waitcnt vmcnt(0)" ::: "memory");
            SBAR();
            #pragma unroll
            for (int i = 0; i < 4; ++i)
                afc[u ^ 1][i] = *(const bf16x8*)(smem + cn + ra + i * 1024);
            #pragma unroll
            for (int i = 0; i < 4; ++i)
                bfc[u ^ 1][i] = *(const bf16x8*)(smem + cn + rb + i * 1024);
            __builtin_amdgcn_s_setprio(1);
            #pragma unroll
            for (int mi = 0; mi < 4; ++mi)
                #pragma unroll
                for (int ni = 0; ni < 4; ++ni)
                    acc[4 + mi][ni] = MFMA_BF16(afB[mi], bfc[u][ni], acc[4 + mi][ni]);
            __builtin_amdgcn_s_setprio(0);
        }
    }
    #undef STAGE_A
    #undef STAGE_B

    const size_t nQKV = (size_t)BB * HH * SS * DHH;
    #pragma unroll
    for (int mi = 0; mi < 8; ++mi) {
        #pragma unroll
        for (int ni = 0; ni < 4; ++ni) {
            #pragma unroll
            for (int rr = 0; rr < 4; ++rr) {
                int m = m0 + wr * 128 + mi * 16 + quad * 4 + rr;
                int n = n0 + wc * 64 + ni * 16 + l15;
                if (EPI == 2) {
                    int h = m >> 6, dl = m & 63;
                    int b = n >> 11, s = n & (SS - 1);
                    __bf16* vt = (__bf16*)outp;
                    vt[(((size_t)b * HH + h) * DHH + dl + qkv_off) * SS + s] = (__bf16)acc[mi][ni][rr];
                } else {  // EPI 4
                    int b = m >> 11, s = m & (SS - 1);
                    int n1 = n & 1023;
                    int h = n1 >> 6, d = (n1 & 63) + qkv_off;
                    if (n < 1024) {
                        __bf16* q = (__bf16*)outp;
                        q[(((size_t)b * HH + h) * SS + s) * DHH + d] = (__bf16)(acc[mi][ni][rr] * SL2E);
                    } else {
                        int dsw = (((d >> 3) ^ (s & 15)) << 3) | (d & 7);
                        __bf16* kq = (__bf16*)outp + nQKV;
                        kq[(((size_t)b * HH + h) * SS + s) * DHH + dsw] = (__bf16)acc[mi][ni][rr];
                    }
                }
            }
        }
    }
}

// ---------------------------------------------------------------------------
// Projection GEMM: C = A @ Bt^T + bias, fp32 out.
// Tile 256x128 -> grid 32x8 = 256 blocks (full chip).
// 512 threads = 8 waves (4x2), per-wave 64x64 (acc 4x4 = 64 regs).
// Same pipelined pattern, single phase per tile. Ring-4 x 24KB LDS.
__global__ __launch_bounds__(512, 2)
void gemm_proj_kernel(const __bf16* __restrict__ A, const __bf16* __restrict__ Bt,
                      int K, float* __restrict__ outp, const float* __restrict__ bias) {
    __shared__ __align__(16) char smem[98304];    // 4 x (A 16KB @0 + B 8KB @16384)

    const int tid = threadIdx.x;
    const int wave = tid >> 6, lane = tid & 63;
    const int l15 = lane & 15, quad = lane >> 4;
    const int wr = wave >> 1, wc = wave & 1;      // 4 row-strips x 2 col-halves

    // XCD-aware remap (nwg = 256, multiple of 8)
    const int gx = gridDim.x;
    const int nwg = gx * gridDim.y;
    const int hwl = blockIdx.y * gx + blockIdx.x;
    const int lg  = (hwl & 7) * (nwg >> 3) + (hwl >> 3);
    const int m0 = (lg % gx) * 256, n0 = (lg / gx) * 128;

    const int rA = tid >> 2;
    const int cs = (tid & 3) ^ ((tid >> 4) & 3);
    const __bf16* aS0 = A  + (size_t)(m0 + rA) * K + cs * 8;
    const __bf16* aS1 = aS0 + (size_t)128 * K;
    const __bf16* bS0 = Bt + (size_t)(n0 + rA) * K + cs * 8;   // rA < 128 covers all B rows
    const int ldsA = wave * 1024;
    const int ldsB = 16384 + wave * 1024;

    const int swz = ((quad ^ (l15 >> 2)) & 3) * 16;
    const int ra = (wr * 64 + l15) * 64 + swz;             // + mi*1024 + buf
    const int rb = 16384 + (wc * 64 + l15) * 64 + swz;     // + ni*1024 + buf

    f32x4 acc[4][4] = {};
    bf16x8 afc[2][4], bfc[2][4];
    const int NT = K >> 5;

    #define STAGE_P(tt) do { const int bo_ = ((tt) & 3) * 24576; \
        GLOAD_LDS16(aS0 + (size_t)(tt) * 32, smem + bo_ + ldsA); \
        GLOAD_LDS16(aS1 + (size_t)(tt) * 32, smem + bo_ + ldsA + 8192); \
        GLOAD_LDS16(bS0 + (size_t)(tt) * 32, smem + bo_ + ldsB); } while (0)

    STAGE_P(0); STAGE_P(1); STAGE_P(2);
    asm volatile("s_waitcnt vmcnt(6)" ::: "memory");
    SBAR();
    #pragma unroll
    for (int i = 0; i < 4; ++i) afc[0][i] = *(const bf16x8*)(smem + ra + i * 1024);
    #pragma unroll
    for (int i = 0; i < 4; ++i) bfc[0][i] = *(const bf16x8*)(smem + rb + i * 1024);

    for (int tp = 0; tp < NT / 2; ++tp) {
        #pragma unroll
        for (int u = 0; u < 2; ++u) {
            const int t = 2 * tp + u;
            const int cn = ((t + 1) & 3) * 24576;
            if (t + 3 < NT) STAGE_P(t + 3);
            if (t < NT - 3)       asm volatile("s_waitcnt vmcnt(6)" ::: "memory");
            else if (t == NT - 3) asm volatile("s_waitcnt vmcnt(3)" ::: "memory");
            else if (t == NT - 2) asm volatile("s_waitcnt vmcnt(0)" ::: "memory");
            SBAR();
            #pragma unroll
            for (int i = 0; i < 4; ++i)
                afc[u ^ 1][i] = *(const bf16x8*)(smem + cn + ra + i * 1024);
            #pragma unroll
            for (int i = 0; i < 4; ++i)
                bfc[u ^ 1][i] = *(const bf16x8*)(smem + cn + rb + i * 1024);
            __builtin_amdgcn_s_setprio(1);
            #pragma unroll
            for (int mi = 0; mi < 4; ++mi)
                #pragma unroll
                for (int ni = 0; ni < 4; ++ni)
                    acc[mi][ni] = MFMA_BF16(afc[u][mi], bfc[u][ni], acc[mi][ni]);
            __builtin_amdgcn_s_setprio(0);
        }
    }
    #undef STAGE_P

    #pragma unroll
    for (int mi = 0; mi < 4; ++mi)
        #pragma unroll
        for (int ni = 0; ni < 4; ++ni)
            #pragma unroll
            for (int rr = 0; rr < 4; ++rr) {
                int m = m0 + wr * 64 + mi * 16 + quad * 4 + rr;
                int n = n0 + wc * 64 + ni * 16 + l15;
                outp[(size_t)m * 1024 + n] = acc[mi][ni][rr] + bias[n];
            }
}

// ---------------------------------------------------------------------------
// Flash attention (no-max softmax; Q pre-scaled so p = exp2(s) directly).
// Q: [bh][S][128]; Kg: [bh][S][128] chunk-swizzled (chunk^(s&15));
// Vg: [bh][128][S] (V^T); O: [B][S][H*128] bf16.
// ROUND-8: SWAPPED QK (mfma(K,Q)) -> each thread holds P[q=l15+16ms]
// [kv=quad*4+rr], so the P->LDS write is 16 x ds_write_b64 (packed bf16x4)
// per thread-kt instead of 64 x scalar b16 (the round<=7 bank-conflict
// source: constant 1.049e7 SQ_LDS_BANK_CONFLICT). Fragments for K and Q are
// layout-identical under the swap (A-row=kv=l15, B-col=q=l15) -> loads
// unchanged. PV unchanged (par read side identical; write swizzle
// c16' = (nl*2+(quad>>1)) ^ ((l15>>2)&3) is the same involution).
// Row sums: per-thread li_[ms] scalars, reduced across quads (xor 16,32),
// redistributed to O-write lanes by __shfl in the epilogue.
// LDS 80 KB: buf[2] x { Ks 16KB, Vt 16KB } @0, Ps [256][64B] @65536.
// 2 blocks/CU. bh->XCD grouping (512 = 64 bh x 8 mt).
#define LDS_BUFSZ 32768
#define LDS_VT    16384
#define LDS_PS    65536
__global__ __launch_bounds__(256, 2)
void attn_kernel(const __bf16* __restrict__ Q, const __bf16* __restrict__ Kg,
                 const __bf16* __restrict__ Vg, __bf16* __restrict__ O) {
    __shared__ __align__(16) char smem[81920];

    const int t = threadIdx.x;
    const int wave = t >> 6, lane = t & 63;
    const int l15 = lane & 15, quad = lane >> 4;

    // bh->XCD grouping decode (bijective over 512 blocks = 64 bh x 8 mt)
    const int lin = blockIdx.x;
    const int mt = (lin >> 3) & 7;
    const int bh = ((lin >> 6) << 3) + (lin & 7);

    const int b = bh >> 4, h = bh & 15;
    const size_t base  = (size_t)bh * SS * DHH;
    const size_t vbase = (size_t)bh * DHH * SS;

    // K A-frag: addr = l15*256 + swz-chunk*16  (+4096*nl + 8192*hf + buf at use)
    int kaddr[4];
    #pragma unroll
    for (int kst = 0; kst < 4; ++kst)
        kaddr[kst] = l15 * 256 + (((4 * kst + quad) ^ l15) & 15) * 16;
    // Vt B-frag: row d = ds*16+l15 (imm 2048*ds), k-block = hf
    int vaddr[2];
    #pragma unroll
    for (int hf = 0; hf < 2; ++hf)
        vaddr[hf] = LDS_VT + l15 * 128 + (((4 * hf + quad) ^ (l15 & 7)) & 7) * 16;
    // Ps b64 write base per nl: row = 64w+16ms+l15 (+1024*ms imm);
    // raw 8B-chunk = nl*4+quad -> 16B chunk (nl*2+(quad>>1)) ^ ((l15>>2)&3),
    // sub-8B = quad&1. 2 accesses/bank (floor) on the 64-bank model.
    int pwN[2];
    #pragma unroll
    for (int nl = 0; nl < 2; ++nl)
        pwN[nl] = LDS_PS + (wave * 64 + l15) * 64 +
                  (((nl * 2 + (quad >> 1)) ^ ((l15 >> 2) & 3)) & 3) * 16 + (quad & 1) * 8;
    // Ps A-frag read base: row = 64w+16ms+l15 -> +1024*ms imm (unchanged)
    const int par = LDS_PS + (wave * 64 + l15) * 64 + ((quad ^ (l15 >> 2)) & 3) * 16;

    // staging source pointers (mt-independent)
    const __bf16* kstage = Kg + base + (size_t)wave * 2048 + lane * 8;
    const __bf16* vstage = Vg + vbase + (size_t)(wave * 32 + (lane >> 3)) * SS
                           + ((lane & 7) ^ ((lane >> 3) & 7)) * 8;

    // stage KV tile kt into buffer at byte offset bo (0 or LDS_BUFSZ)
    #define STAGE_KV(kt_, bo_) do { \
        _Pragma("unroll") \
        for (int i_ = 0; i_ < 4; ++i_) \
            GLOAD_LDS16(kstage + (size_t)(kt_) * 8192 + i_ * 512, \
                        smem + (bo_) + wave * 4096 + i_ * 1024); \
        _Pragma("unroll") \
        for (int i_ = 0; i_ < 4; ++i_) \
            GLOAD_LDS16(vstage + (kt_) * 64 + (size_t)i_ * 8 * SS, \
                        smem + (bo_) + LDS_VT + wave * 4096 + i_ * 1024); \
    } while (0)

    // Q fragments (B-operand under swap; same layout), rows mt*256+wave*64+ms*16+l15
    bf16x8 qf[4][4];
    #pragma unroll
    for (int ms = 0; ms < 4; ++ms) {
        int row = mt * 256 + wave * 64 + ms * 16 + l15;
        #pragma unroll
        for (int kst = 0; kst < 4; ++kst)
            qf[ms][kst] = *(const bf16x8*)(Q + base + (size_t)row * DHH + kst * 32 + quad * 8);
    }

    f32x4 oacc[4][8] = {};
    float li_[4] = {};

    STAGE_KV(0, 0);
    __syncthreads();   // drain stage(0)

    for (int kt = 0; kt < SS / 64; ++kt) {
        const int co = (kt & 1) * LDS_BUFSZ;
        if (kt + 1 < SS / 64) STAGE_KV(kt + 1, co ^ LDS_BUFSZ);

        #pragma unroll
        for (int hf = 0; hf < 2; ++hf) {
            // ---- swapped QK for kv half hf, one nl column-block at a time ----
            #pragma unroll
            for (int nl = 0; nl < 2; ++nl) {
                f32x4 sxn[4] = {};
                __builtin_amdgcn_s_setprio(1);
                #pragma unroll
                for (int kst = 0; kst < 4; ++kst) {
                    bf16x8 kf = *(const bf16x8*)(smem + co + kaddr[kst] + 8192 * hf + 4096 * nl);
                    sxn[0] = MFMA_BF16(kf, qf[0][kst], sxn[0]);
                    sxn[1] = MFMA_BF16(kf, qf[1][kst], sxn[1]);
                    sxn[2] = MFMA_BF16(kf, qf[2][kst], sxn[2]);
                    sxn[3] = MFMA_BF16(kf, qf[3][kst], sxn[3]);
                }
                __builtin_amdgcn_s_setprio(0);
                // p = exp2(s); per-thread row-sum (q = l15+16ms); packed b64 write
                #pragma unroll
                for (int ms = 0; ms < 4; ++ms) {
                    bf16x4 pk;
                    #pragma unroll
                    for (int rr = 0; rr < 4; ++rr) {
                        float p = EXP2(sxn[ms][rr]);
                        li_[ms] += p;
                        pk[rr] = (__bf16)p;
                    }
                    *(bf16x4*)(smem + pwN[nl] + 1024 * ms) = pk;
                }
            }

            // ---- O += P-half @ V-half ----
            bf16x8 pa[4];
            #pragma unroll
            for (int ms = 0; ms < 4; ++ms)
                pa[ms] = *(const bf16x8*)(smem + par + 1024 * ms);
            __builtin_amdgcn_s_setprio(1);
            #pragma unroll
            for (int ds = 0; ds < 8; ++ds) {
                bf16x8 vf = *(const bf16x8*)(smem + co + vaddr[hf] + 2048 * ds);
                oacc[0][ds] = MFMA_BF16(pa[0], vf, oacc[0][ds]);
                oacc[1][ds] = MFMA_BF16(pa[1], vf, oacc[1][ds]);
                oacc[2][ds] = MFMA_BF16(pa[2], vf, oacc[2][ds]);
                oacc[3][ds] = MFMA_BF16(pa[3], vf, oacc[3][ds]);
            }
            __builtin_amdgcn_s_setprio(0);
        }
        // one barrier per kt: drains stage(kt+1) DMA (vmcnt) and orders all-wave
        // reads of buf(kt) before stage(kt+2) overwrites it next iteration
        __syncthreads();
    }
    #undef STAGE_KV

    // epilogue: li_[ms] holds this thread's partial sum for q-row l15+16ms;
    // reduce across the 4 quads sharing that row (lane bits 4,5)
    #pragma unroll
    for (int ms = 0; ms < 4; ++ms) {
        float v = li_[ms];
        v += __shfl_xor(v, 16);
        v += __shfl_xor(v, 32);
        li_[ms] = 1.f / v;
    }

    // O rows are quad*4+rr (PV C-layout); fetch that row's 1/sum via shfl
    #pragma unroll
    for (int ms = 0; ms < 4; ++ms)
        #pragma unroll
        for (int rr = 0; rr < 4; ++rr) {
            float sc = __shfl(li_[ms], (lane & 48) | (quad * 4 + rr));
            int s = mt * 256 + wave * 64 + ms * 16 + quad * 4 + rr;
            size_t ob = ((size_t)b * SS + s) * (HH * DHH) + (size_t)h * DHH;
            #pragma unroll
            for (int ds = 0; ds < 8; ++ds)
                O[ob + ds * 16 + l15] = (__bf16)(oacc[ms][ds][rr] * sc);
        }
}

// ---------------------------------------------------------------------------
extern "C" void kernel_launch(void* const* d_in, const int* in_sizes, int n_in,
                              void* d_out, int out_size, void* d_ws, size_t ws_size,
                              hipStream_t stream) {
    const float* x      = (const float*)d_in[0];
    const float* c      = (const float*)d_in[1];
    const float* Wq_x   = (const float*)d_in[2];
    const float* Wk_x   = (const float*)d_in[3];
    const float* Wv_x   = (const float*)d_in[4];
    const float* Wq_c   = (const float*)d_in[5];
    const float* Wk_c   = (const float*)d_in[6];
    const float* Wv_c   = (const float*)d_in[7];
    const float* W_proj = (const float*)d_in[8];
    const float* b_proj = (const float*)d_in[9];

    const size_t nXC  = (size_t)BB * SS * DD;
    const size_t nW   = (size_t)DD * DD;
    const size_t nWP  = (size_t)(2 * HH * 64) * DD;
    const size_t nQKV = (size_t)BB * HH * SS * DHH;

    __bf16* ws  = (__bf16*)d_ws;
    __bf16* xb  = ws;
    __bf16* cb  = xb + nXC;
    __bf16* wt0 = cb + nXC;          // [Wq_x; Wk_x; Wv_x; Wq_c; Wk_c; Wv_c]^T contiguous
    __bf16* wt2 = wt0 + 2 * nW;      // Wv_x^T
    __bf16* wt3 = wt0 + 3 * nW;      // Wq_c^T (c's Q,K pair start)
    __bf16* wt5 = wt0 + 5 * nW;      // Wv_c^T
    __bf16* wtp = wt0 + 6 * nW;      // W_proj^T [1024][2048]
    __bf16* Qb  = wtp + nWP;
    __bf16* Kb  = Qb + nQKV;         // MUST stay at Qb + nQKV (EPI4 assumes it)
    __bf16* Vb  = Kb + nQKV;         // [B*H][128][S] pre-transposed
    __bf16* Ob  = xb;                // alias x/c region (dead after QKV GEMMs)

    cast2_kernel<<<(int)(2 * nXC / 1024), 256, 0, stream>>>(x, c, xb, (int)nXC);

    transpose6_kernel<<<dim3(32, 32, 6), dim3(32, 8), 0, stream>>>(
        Wq_x, Wk_x, Wv_x, Wq_c, Wk_c, Wv_c, wt0);
    transpose_cast_kernel<<<dim3(32, 64), dim3(32, 8), 0, stream>>>(W_proj, wtp, 2048, 1024);

    // z-batched fused Q+K GEMMs (M=8192, N=2048, K=1024): z=0 x-path, z=1 c-path
    gemm256_kernel<4><<<dim3(32, 8, 2), 512, 0, stream>>>(xb, cb, wt0, wt3, 1024, Qb, nullptr);
    // z-batched V GEMMs (A = Wv^T, B = activations) -> V^T [bh][d][s]
    gemm256_kernel<2><<<dim3(4, 32, 2), 512, 0, stream>>>(wt2, wt5, xb, cb, 1024, Vb, nullptr);

    // attention (writes Ob = [B,S,H*128] bf16), Q tile 256 -> 512 blocks
    attn_kernel<<<dim3(512), 256, 0, stream>>>(Qb, Kb, Vb, Ob);

    // projection (M=8192, K=2048, N=1024) + bias -> fp32 out, 256x128 tile
    gemm_proj_kernel<<<dim3(32, 8), 512, 0, stream>>>(Ob, wtp, 2048, (float*)d_out, b_proj);
}

// Round 13
// 447.080 us; speedup vs baseline: 1.0168x; 1.0168x over previous
//
#include <hip/hip_runtime.h>
#include <hip/hip_bf16.h>
#include <stdint.h>

// Problem constants
#define BB 4
#define SS 2048
#define DD 1024
#define HH 16
#define DHH 128   // per-head dim after concat (2*64)

typedef __bf16 bf16x8 __attribute__((ext_vector_type(8)));
typedef __bf16 bf16x4 __attribute__((ext_vector_type(4)));
typedef float  f32x4  __attribute__((ext_vector_type(4)));

// (1/sqrt(64)) * log2(e), folded into Q at GEMM epilogue time
#define SL2E 0.180336880111186f

#if __has_builtin(__builtin_amdgcn_exp2f)
#define EXP2(x) __builtin_amdgcn_exp2f(x)
#else
#define EXP2(x) exp2f(x)
#endif

// async global->LDS, 16B per lane; LDS dest is wave-uniform base + lane*16,
// global src is per-lane (gather allowed)
#define GLOAD_LDS16(gp, lp) \
  __builtin_amdgcn_global_load_lds((const __attribute__((address_space(1))) unsigned int*)(gp), \
                                   (__attribute__((address_space(3))) unsigned int*)(lp), 16, 0, 0)

// compiler memory fence around raw s_barrier so LDS ops can't be moved across
#define SBAR() do { asm volatile("" ::: "memory"); \
                    __builtin_amdgcn_s_barrier();  \
                    asm volatile("" ::: "memory"); } while (0)

#define MFMA_BF16(a, b, c) __builtin_amdgcn_mfma_f32_16x16x32_bf16((a), (b), (c), 0, 0, 0)

// ---------------------------------------------------------------------------
// Fused cast of x and c -> bf16 (dest xb and cb are contiguous)
__global__ void cast2_kernel(const float* __restrict__ x, const float* __restrict__ c,
                             __bf16* __restrict__ out, int n) {
    int i = (blockIdx.x * blockDim.x + threadIdx.x) * 4;
    const float* src = (i < n) ? (x + i) : (c + (i - n));
    f32x4 v = *(const f32x4*)src;
    bf16x4 o;
    o[0] = (__bf16)v[0]; o[1] = (__bf16)v[1]; o[2] = (__bf16)v[2]; o[3] = (__bf16)v[3];
    *(bf16x4*)(out + i) = o;
}

// ---------------------------------------------------------------------------
// Transpose + cast: W[K][N] fp32 -> Wt[N][K] bf16 (used for W_proj)
__global__ void transpose_cast_kernel(const float* __restrict__ in, __bf16* __restrict__ out,
                                      int K, int N) {
    __shared__ float tile[32][33];
    int n0 = blockIdx.x * 32, k0 = blockIdx.y * 32;
    int tx = threadIdx.x, ty = threadIdx.y;   // 32 x 8
    #pragma unroll
    for (int i = 0; i < 32; i += 8)
        tile[ty + i][tx] = in[(size_t)(k0 + ty + i) * N + n0 + tx];
    __syncthreads();
    #pragma unroll
    for (int i = 0; i < 32; i += 8)
        out[(size_t)(n0 + ty + i) * K + k0 + tx] = (__bf16)tile[tx][ty + i];
}

// Fused transpose+cast of the six 1024x1024 QKV weights into contiguous dst
// Order: Wq_x, Wk_x, Wv_x, Wq_c, Wk_c, Wv_c  (Q,K adjacent per input for fusion)
__global__ void transpose6_kernel(const float* s0, const float* s1, const float* s2,
                                  const float* s3, const float* s4, const float* s5,
                                  __bf16* __restrict__ dst) {
    const float* srcs[6] = {s0, s1, s2, s3, s4, s5};
    const float* __restrict__ in = srcs[blockIdx.z];
    __bf16* __restrict__ out = dst + (size_t)blockIdx.z * 1024 * 1024;
    __shared__ float tile[32][33];
    int n0 = blockIdx.x * 32, k0 = blockIdx.y * 32;
    int tx = threadIdx.x, ty = threadIdx.y;   // 32 x 8
    #pragma unroll
    for (int i = 0; i < 32; i += 8)
        tile[ty + i][tx] = in[(size_t)(k0 + ty + i) * 1024 + n0 + tx];
    __syncthreads();
    #pragma unroll
    for (int i = 0; i < 32; i += 8)
        out[(size_t)(n0 + ty + i) * 1024 + k0 + tx] = (__bf16)tile[tx][ty + i];
}

// ---------------------------------------------------------------------------
// 256x256 4-phase/K-tile GEMM (m201-style), BK=64: C = A @ Bt^T.
// 512 threads = 8 waves. Wave output 128x64 with INTERLEAVED row mapping
// row = wr*16 + mi*32 (mi 0..7): phase p consumes exactly A-quarter p
// (rows 64p..64p+63) for BOTH wr groups. B strip (wc*64..+63) = one
// B-quarter per wave, resident whole tile.
// LDS 128 KB: A ring-2 (0, 32768), B ring-2 (65536, 98304); 128 B rows.
// Full 3-bit chunk swizzle c' = c ^ (row&7) -> ds_read_b128 at the
// 8-dword/bank floor; staged linearly with pre-swizzled global source
// (cs = (lane&7) ^ ((lane>>3)&7); both-sides rule).
// Staging: B(T+1) whole (4 loads) at phase 0; A(T+1) quarter p at phase p.
// Counted waits (per-wave outstanding = 8 steady): vmcnt(7) phases 0-2
// forces A(T)q_{p+1}; vmcnt(3) phase 3 forces B(T+1)+A(T+1)q0. Never
// drains mid-loop; last tile uses vmcnt(2/1/0). Two barriers per phase
// (coverage + write-after-read). 16 MFMA/phase under setprio(1).
// EPI 2: V^T epilogue; EPI 4: fused Q+K epilogue (same semantics as before,
// only the m formula reflects the interleaved row mapping).
template <int EPI>
__global__ __launch_bounds__(512, 2)
void gemm8p_kernel(const __bf16* __restrict__ A0, const __bf16* __restrict__ A1,
                   const __bf16* __restrict__ B0, const __bf16* __restrict__ B1,
                   int K, void* __restrict__ outp) {
    const int z = blockIdx.z;
    const __bf16* __restrict__ A  = z ? A1 : A0;
    const __bf16* __restrict__ Bt = z ? B1 : B0;
    const int qkv_off = z * 64;

    __shared__ __align__(16) char smem[131072];

    const int tid = threadIdx.x;
    const int wave = tid >> 6, lane = tid & 63;
    const int l15 = lane & 15, quad = lane >> 4;
    const int wr = wave >> 2, wc = wave & 3;

    // XCD-aware block remap (bijective: nwg per z is a multiple of 8)
    const int gx = gridDim.x;
    const int nwg = gx * gridDim.y;
    const int hwl = blockIdx.y * gx + blockIdx.x;
    const int lg  = (hwl & 7) * (nwg >> 3) + (hwl >> 3);
    const int m0 = (lg % gx) * 256, n0 = (lg / gx) * 256;

    // staging: per gload, wave covers rows wave*8 + lane/8 of an 8-row band;
    // source chunk pre-swizzled so LDS[row][c] = global[row][c ^ (row&7)]
    const int cs = (lane & 7) ^ ((lane >> 3) & 7);
    const __bf16* aSt = A  + (size_t)(m0 + wave * 8 + (lane >> 3)) * K + cs * 8;
    const __bf16* bSt = Bt + (size_t)(n0 + wave * 8 + (lane >> 3)) * K + cs * 8;
    const int ldso = wave * 1024;

    // read bases: byte = row*128 + ((quad+4kk) ^ (row&7))*16; row&7 = l15&7
    const int fsw = l15 & 7;
    const int cks0 = ((quad ^ fsw) & 7) * 16;
    const int cks1 = (((quad + 4) ^ fsw) & 7) * 16;
    const int ra0 = (wr * 16 + l15) * 128;     // + mi*4096 + Abuf
    const int rb0 = (wc * 64 + l15) * 128;     // + ni*2048 + Bbuf

    f32x4 acc[8][4] = {};
    const int NT = K >> 6;

    #define STG_A(T_, q_) GLOAD_LDS16(aSt + (size_t)(q_) * 64 * K + (T_) * 64, \
        smem + ((T_) & 1) * 32768 + (q_) * 8192 + ldso)
    #define STG_B(T_) do { _Pragma("unroll") \
        for (int j_ = 0; j_ < 4; ++j_) \
            GLOAD_LDS16(bSt + (size_t)j_ * 64 * K + (T_) * 64, \
                smem + 65536 + ((T_) & 1) * 32768 + j_ * 8192 + ldso); } while (0)

    // prologue: B(0) then A(0)q0..3; wait so B(0)+A(0)q0 complete (3 newest ok)
    STG_B(0);
    STG_A(0, 0); STG_A(0, 1); STG_A(0, 2); STG_A(0, 3);
    asm volatile("s_waitcnt vmcnt(3)" ::: "memory");
    SBAR();

    for (int T = 0; T < NT; ++T) {
        const int ca = (T & 1) * 32768;
        const int cb = 65536 + (T & 1) * 32768;
        const bool stg = (T + 1 < NT);
        bf16x8 bfr[4][2];
        #pragma unroll
        for (int p = 0; p < 4; ++p) {
            // ---- reads for THIS phase (covered by previous vmcnt+SBAR) ----
            bf16x8 af[2][2];
            #pragma unroll
            for (int ml = 0; ml < 2; ++ml) {
                af[ml][0] = *(const bf16x8*)(smem + ca + ra0 + (2 * p + ml) * 4096 + cks0);
                af[ml][1] = *(const bf16x8*)(smem + ca + ra0 + (2 * p + ml) * 4096 + cks1);
            }
            if (p == 0) {
                #pragma unroll
                for (int ni = 0; ni < 4; ++ni) {
                    bfr[ni][0] = *(const bf16x8*)(smem + cb + rb0 + ni * 2048 + cks0);
                    bfr[ni][1] = *(const bf16x8*)(smem + cb + rb0 + ni * 2048 + cks1);
                }
            }
            // ---- stage next tile ----
            if (stg) {
                if (p == 0) STG_B(T + 1);
                STG_A(T + 1, p);
            }
            // ---- counted wait (forces exactly the next needed region) ----
            if (p == 0)      { if (stg) asm volatile("s_waitcnt vmcnt(7)" ::: "memory");
                               else    asm volatile("s_waitcnt vmcnt(2)" ::: "memory"); }
            else if (p == 1) { if (stg) asm volatile("s_waitcnt vmcnt(7)" ::: "memory");
                               else    asm volatile("s_waitcnt vmcnt(1)" ::: "memory"); }
            else if (p == 2) { if (stg) asm volatile("s_waitcnt vmcnt(7)" ::: "memory");
                               else    asm volatile("s_waitcnt vmcnt(0)" ::: "memory"); }
            else             { if (stg) asm volatile("s_waitcnt vmcnt(3)" ::: "memory"); }
            SBAR();
            // ---- 16 MFMA: mi {2p,2p+1} x ni 0-3 x kk 0-1 ----
            __builtin_amdgcn_s_setprio(1);
            #pragma unroll
            for (int kk = 0; kk < 2; ++kk)
                #pragma unroll
                for (int ml = 0; ml < 2; ++ml)
                    #pragma unroll
                    for (int ni = 0; ni < 4; ++ni)
                        acc[2 * p + ml][ni] = MFMA_BF16(af[ml][kk], bfr[ni][kk], acc[2 * p + ml][ni]);
            __builtin_amdgcn_s_setprio(0);
            SBAR();   // write-after-read: all waves consumed before next stage lands
        }
    }
    #undef STG_A
    #undef STG_B

    const size_t nQKV = (size_t)BB * HH * SS * DHH;
    #pragma unroll
    for (int mi = 0; mi < 8; ++mi) {
        #pragma unroll
        for (int ni = 0; ni < 4; ++ni) {
            #pragma unroll
            for (int rr = 0; rr < 4; ++rr) {
                int m = m0 + wr * 16 + mi * 32 + quad * 4 + rr;   // interleaved mapping
                int n = n0 + wc * 64 + ni * 16 + l15;
                if (EPI == 2) {
                    int h = m >> 6, dl = m & 63;
                    int b = n >> 11, s = n & (SS - 1);
                    __bf16* vt = (__bf16*)outp;
                    vt[(((size_t)b * HH + h) * DHH + dl + qkv_off) * SS + s] = (__bf16)acc[mi][ni][rr];
                } else {  // EPI 4
                    int b = m >> 11, s = m & (SS - 1);
                    int n1 = n & 1023;
                    int h = n1 >> 6, d = (n1 & 63) + qkv_off;
                    if (n < 1024) {
                        __bf16* q = (__bf16*)outp;
                        q[(((size_t)b * HH + h) * SS + s) * DHH + d] = (__bf16)(acc[mi][ni][rr] * SL2E);
                    } else {
                        int dsw = (((d >> 3) ^ (s & 15)) << 3) | (d & 7);
                        __bf16* kq = (__bf16*)outp + nQKV;
                        kq[(((size_t)b * HH + h) * SS + s) * DHH + dsw] = (__bf16)acc[mi][ni][rr];
                    }
                }
            }
        }
    }
}

// ---------------------------------------------------------------------------
// Projection GEMM: C = A @ Bt^T + bias, fp32 out.
// Tile 256x128 -> grid 32x8 = 256 blocks (full chip).
// 512 threads = 8 waves (4x2), per-wave 64x64 (acc 4x4 = 64 regs).
// Pipelined: ring-4 x 24KB LDS, one-phase-ahead fragment reads, counted vmcnt.
__global__ __launch_bounds__(512, 2)
void gemm_proj_kernel(const __bf16* __restrict__ A, const __bf16* __restrict__ Bt,
                      int K, float* __restrict__ outp, const float* __restrict__ bias) {
    __shared__ __align__(16) char smem[98304];    // 4 x (A 16KB @0 + B 8KB @16384)

    const int tid = threadIdx.x;
    const int wave = tid >> 6, lane = tid & 63;
    const int l15 = lane & 15, quad = lane >> 4;
    const int wr = wave >> 1, wc = wave & 1;      // 4 row-strips x 2 col-halves

    // XCD-aware remap (nwg = 256, multiple of 8)
    const int gx = gridDim.x;
    const int nwg = gx * gridDim.y;
    const int hwl = blockIdx.y * gx + blockIdx.x;
    const int lg  = (hwl & 7) * (nwg >> 3) + (hwl >> 3);
    const int m0 = (lg % gx) * 256, n0 = (lg / gx) * 128;

    const int rA = tid >> 2;
    const int cs = (tid & 3) ^ ((tid >> 4) & 3);
    const __bf16* aS0 = A  + (size_t)(m0 + rA) * K + cs * 8;
    const __bf16* aS1 = aS0 + (size_t)128 * K;
    const __bf16* bS0 = Bt + (size_t)(n0 + rA) * K + cs * 8;   // rA < 128 covers all B rows
    const int ldsA = wave * 1024;
    const int ldsB = 16384 + wave * 1024;

    const int swz = ((quad ^ (l15 >> 2)) & 3) * 16;
    const int ra = (wr * 64 + l15) * 64 + swz;             // + mi*1024 + buf
    const int rb = 16384 + (wc * 64 + l15) * 64 + swz;     // + ni*1024 + buf

    f32x4 acc[4][4] = {};
    bf16x8 afc[2][4], bfc[2][4];
    const int NT = K >> 5;

    #define STAGE_P(tt) do { const int bo_ = ((tt) & 3) * 24576; \
        GLOAD_LDS16(aS0 + (size_t)(tt) * 32, smem + bo_ + ldsA); \
        GLOAD_LDS16(aS1 + (size_t)(tt) * 32, smem + bo_ + ldsA + 8192); \
        GLOAD_LDS16(bS0 + (size_t)(tt) * 32, smem + bo_ + ldsB); } while (0)

    STAGE_P(0); STAGE_P(1); STAGE_P(2);
    asm volatile("s_waitcnt vmcnt(6)" ::: "memory");
    SBAR();
    #pragma unroll
    for (int i = 0; i < 4; ++i) afc[0][i] = *(const bf16x8*)(smem + ra + i * 1024);
    #pragma unroll
    for (int i = 0; i < 4; ++i) bfc[0][i] = *(const bf16x8*)(smem + rb + i * 1024);

    for (int tp = 0; tp < NT / 2; ++tp) {
        #pragma unroll
        for (int u = 0; u < 2; ++u) {
            const int t = 2 * tp + u;
            const int cn = ((t + 1) & 3) * 24576;
            if (t + 3 < NT) STAGE_P(t + 3);
            if (t < NT - 3)       asm volatile("s_waitcnt vmcnt(6)" ::: "memory");
            else if (t == NT - 3) asm volatile("s_waitcnt vmcnt(3)" ::: "memory");
            else if (t == NT - 2) asm volatile("s_waitcnt vmcnt(0)" ::: "memory");
            SBAR();
            #pragma unroll
            for (int i = 0; i < 4; ++i)
                afc[u ^ 1][i] = *(const bf16x8*)(smem + cn + ra + i * 1024);
            #pragma unroll
            for (int i = 0; i < 4; ++i)
                bfc[u ^ 1][i] = *(const bf16x8*)(smem + cn + rb + i * 1024);
            __builtin_amdgcn_s_setprio(1);
            #pragma unroll
            for (int mi = 0; mi < 4; ++mi)
                #pragma unroll
                for (int ni = 0; ni < 4; ++ni)
                    acc[mi][ni] = MFMA_BF16(afc[u][mi], bfc[u][ni], acc[mi][ni]);
            __builtin_amdgcn_s_setprio(0);
        }
    }
    #undef STAGE_P

    #pragma unroll
    for (int mi = 0; mi < 4; ++mi)
        #pragma unroll
        for (int ni = 0; ni < 4; ++ni)
            #pragma unroll
            for (int rr = 0; rr < 4; ++rr) {
                int m = m0 + wr * 64 + mi * 16 + quad * 4 + rr;
                int n = n0 + wc * 64 + ni * 16 + l15;
                outp[(size_t)m * 1024 + n] = acc[mi][ni][rr] + bias[n];
            }
}

// ---------------------------------------------------------------------------
// Flash attention (no-max softmax; Q pre-scaled so p = exp2(s) directly).
// SWAPPED QK (mfma(K,Q)): thread holds P[q=l15+16ms][kv=quad*4+rr] ->
// P->LDS is packed ds_write_b64 (proven: conflicts 10.49M -> 6.29M).
// Q tile 256 (64 rows/wave, ms=4) -> 512 blocks; bh->XCD grouping.
// LDS 80 KB: buf[2] x { Ks 16KB, Vt 16KB } @0, Ps [256][64B] @65536.
#define LDS_BUFSZ 32768
#define LDS_VT    16384
#define LDS_PS    65536
__global__ __launch_bounds__(256, 2)
void attn_kernel(const __bf16* __restrict__ Q, const __bf16* __restrict__ Kg,
                 const __bf16* __restrict__ Vg, __bf16* __restrict__ O) {
    __shared__ __align__(16) char smem[81920];

    const int t = threadIdx.x;
    const int wave = t >> 6, lane = t & 63;
    const int l15 = lane & 15, quad = lane >> 4;

    // bh->XCD grouping decode (bijective over 512 blocks = 64 bh x 8 mt)
    const int lin = blockIdx.x;
    const int mt = (lin >> 3) & 7;
    const int bh = ((lin >> 6) << 3) + (lin & 7);

    const int b = bh >> 4, h = bh & 15;
    const size_t base  = (size_t)bh * SS * DHH;
    const size_t vbase = (size_t)bh * DHH * SS;

    // K A-frag: addr = l15*256 + swz-chunk*16  (+4096*nl + 8192*hf + buf at use)
    int kaddr[4];
    #pragma unroll
    for (int kst = 0; kst < 4; ++kst)
        kaddr[kst] = l15 * 256 + (((4 * kst + quad) ^ l15) & 15) * 16;
    // Vt B-frag: row d = ds*16+l15 (imm 2048*ds), k-block = hf
    int vaddr[2];
    #pragma unroll
    for (int hf = 0; hf < 2; ++hf)
        vaddr[hf] = LDS_VT + l15 * 128 + (((4 * hf + quad) ^ (l15 & 7)) & 7) * 16;
    // Ps b64 write base per nl: row = 64w+16ms+l15 (+1024*ms imm);
    // 16B chunk (nl*2+(quad>>1)) ^ ((l15>>2)&3), sub-8B = quad&1.
    int pwN[2];
    #pragma unroll
    for (int nl = 0; nl < 2; ++nl)
        pwN[nl] = LDS_PS + (wave * 64 + l15) * 64 +
                  (((nl * 2 + (quad >> 1)) ^ ((l15 >> 2) & 3)) & 3) * 16 + (quad & 1) * 8;
    // Ps A-frag read base: row = 64w+16ms+l15 -> +1024*ms imm
    const int par = LDS_PS + (wave * 64 + l15) * 64 + ((quad ^ (l15 >> 2)) & 3) * 16;

    // staging source pointers (mt-independent)
    const __bf16* kstage = Kg + base + (size_t)wave * 2048 + lane * 8;
    const __bf16* vstage = Vg + vbase + (size_t)(wave * 32 + (lane >> 3)) * SS
                           + ((lane & 7) ^ ((lane >> 3) & 7)) * 8;

    // stage KV tile kt into buffer at byte offset bo (0 or LDS_BUFSZ)
    #define STAGE_KV(kt_, bo_) do { \
        _Pragma("unroll") \
        for (int i_ = 0; i_ < 4; ++i_) \
            GLOAD_LDS16(kstage + (size_t)(kt_) * 8192 + i_ * 512, \
                        smem + (bo_) + wave * 4096 + i_ * 1024); \
        _Pragma("unroll") \
        for (int i_ = 0; i_ < 4; ++i_) \
            GLOAD_LDS16(vstage + (kt_) * 64 + (size_t)i_ * 8 * SS, \
                        smem + (bo_) + LDS_VT + wave * 4096 + i_ * 1024); \
    } while (0)

    // Q fragments (B-operand under swap), rows mt*256 + wave*64 + ms*16 + l15
    bf16x8 qf[4][4];
    #pragma unroll
    for (int ms = 0; ms < 4; ++ms) {
        int row = mt * 256 + wave * 64 + ms * 16 + l15;
        #pragma unroll
        for (int kst = 0; kst < 4; ++kst)
            qf[ms][kst] = *(const bf16x8*)(Q + base + (size_t)row * DHH + kst * 32 + quad * 8);
    }

    f32x4 oacc[4][8] = {};
    float li_[4] = {};

    STAGE_KV(0, 0);
    __syncthreads();   // drain stage(0)

    for (int kt = 0; kt < SS / 64; ++kt) {
        const int co = (kt & 1) * LDS_BUFSZ;
        if (kt + 1 < SS / 64) STAGE_KV(kt + 1, co ^ LDS_BUFSZ);

        #pragma unroll
        for (int hf = 0; hf < 2; ++hf) {
            // ---- swapped QK for kv half hf, one nl column-block at a time ----
            #pragma unroll
            for (int nl = 0; nl < 2; ++nl) {
                f32x4 sxn[4] = {};
                __builtin_amdgcn_s_setprio(1);
                #pragma unroll
                for (int kst = 0; kst < 4; ++kst) {
                    bf16x8 kf = *(const bf16x8*)(smem + co + kaddr[kst] + 8192 * hf + 4096 * nl);
                    sxn[0] = MFMA_BF16(kf, qf[0][kst], sxn[0]);
                    sxn[1] = MFMA_BF16(kf, qf[1][kst], sxn[1]);
                    sxn[2] = MFMA_BF16(kf, qf[2][kst], sxn[2]);
                    sxn[3] = MFMA_BF16(kf, qf[3][kst], sxn[3]);
                }
                __builtin_amdgcn_s_setprio(0);
                // p = exp2(s); per-thread row-sum (q = l15+16ms); packed b64 write
                #pragma unroll
                for (int ms = 0; ms < 4; ++ms) {
                    bf16x4 pk;
                    #pragma unroll
                    for (int rr = 0; rr < 4; ++rr) {
                        float p = EXP2(sxn[ms][rr]);
                        li_[ms] += p;
                        pk[rr] = (__bf16)p;
                    }
                    *(bf16x4*)(smem + pwN[nl] + 1024 * ms) = pk;
                }
            }

            // ---- O += P-half @ V-half ----
            bf16x8 pa[4];
            #pragma unroll
            for (int ms = 0; ms < 4; ++ms)
                pa[ms] = *(const bf16x8*)(smem + par + 1024 * ms);
            __builtin_amdgcn_s_setprio(1);
            #pragma unroll
            for (int ds = 0; ds < 8; ++ds) {
                bf16x8 vf = *(const bf16x8*)(smem + co + vaddr[hf] + 2048 * ds);
                oacc[0][ds] = MFMA_BF16(pa[0], vf, oacc[0][ds]);
                oacc[1][ds] = MFMA_BF16(pa[1], vf, oacc[1][ds]);
                oacc[2][ds] = MFMA_BF16(pa[2], vf, oacc[2][ds]);
                oacc[3][ds] = MFMA_BF16(pa[3], vf, oacc[3][ds]);
            }
            __builtin_amdgcn_s_setprio(0);
        }
        __syncthreads();
    }
    #undef STAGE_KV

    // epilogue: li_[ms] partial for q-row l15+16ms; reduce across quads
    #pragma unroll
    for (int ms = 0; ms < 4; ++ms) {
        float v = li_[ms];
        v += __shfl_xor(v, 16);
        v += __shfl_xor(v, 32);
        li_[ms] = 1.f / v;
    }

    // O rows are quad*4+rr (PV C-layout); fetch that row's 1/sum via shfl
    #pragma unroll
    for (int ms = 0; ms < 4; ++ms)
        #pragma unroll
        for (int rr = 0; rr < 4; ++rr) {
            float sc = __shfl(li_[ms], (lane & 48) | (quad * 4 + rr));
            int s = mt * 256 + wave * 64 + ms * 16 + quad * 4 + rr;
            size_t ob = ((size_t)b * SS + s) * (HH * DHH) + (size_t)h * DHH;
            #pragma unroll
            for (int ds = 0; ds < 8; ++ds)
                O[ob + ds * 16 + l15] = (__bf16)(oacc[ms][ds][rr] * sc);
        }
}

// ---------------------------------------------------------------------------
extern "C" void kernel_launch(void* const* d_in, const int* in_sizes, int n_in,
                              void* d_out, int out_size, void* d_ws, size_t ws_size,
                              hipStream_t stream) {
    const float* x      = (const float*)d_in[0];
    const float* c      = (const float*)d_in[1];
    const float* Wq_x   = (const float*)d_in[2];
    const float* Wk_x   = (const float*)d_in[3];
    const float* Wv_x   = (const float*)d_in[4];
    const float* Wq_c   = (const float*)d_in[5];
    const float* Wk_c   = (const float*)d_in[6];
    const float* Wv_c   = (const float*)d_in[7];
    const float* W_proj = (const float*)d_in[8];
    const float* b_proj = (const float*)d_in[9];

    const size_t nXC  = (size_t)BB * SS * DD;
    const size_t nW   = (size_t)DD * DD;
    const size_t nWP  = (size_t)(2 * HH * 64) * DD;
    const size_t nQKV = (size_t)BB * HH * SS * DHH;

    __bf16* ws  = (__bf16*)d_ws;
    __bf16* xb  = ws;
    __bf16* cb  = xb + nXC;
    __bf16* wt0 = cb + nXC;          // [Wq_x; Wk_x; Wv_x; Wq_c; Wk_c; Wv_c]^T contiguous
    __bf16* wt2 = wt0 + 2 * nW;      // Wv_x^T
    __bf16* wt3 = wt0 + 3 * nW;      // Wq_c^T (c's Q,K pair start)
    __bf16* wt5 = wt0 + 5 * nW;      // Wv_c^T
    __bf16* wtp = wt0 + 6 * nW;      // W_proj^T [1024][2048]
    __bf16* Qb  = wtp + nWP;
    __bf16* Kb  = Qb + nQKV;         // MUST stay at Qb + nQKV (EPI4 assumes it)
    __bf16* Vb  = Kb + nQKV;         // [B*H][128][S] pre-transposed
    __bf16* Ob  = xb;                // alias x/c region (dead after QKV GEMMs)

    cast2_kernel<<<(int)(2 * nXC / 1024), 256, 0, stream>>>(x, c, xb, (int)nXC);

    transpose6_kernel<<<dim3(32, 32, 6), dim3(32, 8), 0, stream>>>(
        Wq_x, Wk_x, Wv_x, Wq_c, Wk_c, Wv_c, wt0);
    transpose_cast_kernel<<<dim3(32, 64), dim3(32, 8), 0, stream>>>(W_proj, wtp, 2048, 1024);

    // z-batched fused Q+K GEMMs (M=8192, N=2048, K=1024): z=0 x-path, z=1 c-path
    gemm8p_kernel<4><<<dim3(32, 8, 2), 512, 0, stream>>>(xb, cb, wt0, wt3, 1024, Qb);
    // z-batched V GEMMs (A = Wv^T, B = activations) -> V^T [bh][d][s]
    gemm8p_kernel<2><<<dim3(4, 32, 2), 512, 0, stream>>>(wt2, wt5, xb, cb, 1024, Vb);

    // attention (writes Ob = [B,S,H*128] bf16), Q tile 256 -> 512 blocks
    attn_kernel<<<dim3(512), 256, 0, stream>>>(Qb, Kb, Vb, Ob);

    // projection (M=8192, K=2048, N=1024) + bias -> fp32 out, 256x128 tile
    gemm_proj_kernel<<<dim3(32, 8), 512, 0, stream>>>(Ob, wtp, 2048, (float*)d_out, b_proj);
}